// Round 11
// baseline (279.273 us; speedup 1.0000x reference)
//
#include <hip/hip_runtime.h>
#include <hip/hip_bf16.h>

typedef __attribute__((ext_vector_type(8))) short short8;
typedef __attribute__((ext_vector_type(4))) float f32x4;

// X: (32, 256, 64, 64) f32 ; W,B: (256, 256, 2, 2) f32 ; out: (32, 256, 128, 128) f32
// GEMM view: M = 131072 pixels (m = n*4096 + ih*64 + iw), N = 1024 (col = o*4 + kh*2 + kw), K = 256.
// Fragment-tiled scratch layout: element (row, k) lives at
//   ((G*8 + K)*64 + g*16 + l15)*8 + j,  G=row>>4, l15=row&15, K=k>>5, g=(k>>3)&3, j=k&7
// so a wave's MFMA fragment load is base + lane*16B -> one coalesced 1KB instruction.

__device__ __forceinline__ short f2bf(float f) {
    union { __hip_bfloat16 h; short s; } u; u.h = __float2bfloat16(f); return u.s;
}

// ---- fast-path preps (unchanged from round 8) ----

__global__ __launch_bounds__(256) void prep_wb2(
    const float* __restrict__ W, const float* __restrict__ B,
    short* __restrict__ Bg2, float* __restrict__ bsum)
{
    const int o = blockIdx.x, c = threadIdx.x;
    const int wave = c >> 6, lane = c & 63;
    f32x4 w = *(const f32x4*)(W + ((size_t)o << 10) + (c << 2));
    const int C = o >> 2;
    const int K = c >> 5, g = (c >> 3) & 3, j = c & 7;
    #pragma unroll
    for (int kl = 0; kl < 4; ++kl) {
        const int l15 = ((o & 3) << 2) + kl;
        Bg2[(size_t)((((C << 3) | K) << 9) + (((g << 4) | l15) << 3) + j)] = f2bf(w[kl]);
    }

    f32x4 b = *(const f32x4*)(B + ((size_t)o << 10) + (c << 2));
    #pragma unroll
    for (int off = 32; off >= 1; off >>= 1) {
        b[0] += __shfl_down(b[0], off, 64);
        b[1] += __shfl_down(b[1], off, 64);
        b[2] += __shfl_down(b[2], off, 64);
        b[3] += __shfl_down(b[3], off, 64);
    }
    __shared__ float red[4][4];
    if (lane == 0) { red[wave][0] = b[0]; red[wave][1] = b[1]; red[wave][2] = b[2]; red[wave][3] = b[3]; }
    __syncthreads();
    if (c < 4)
        bsum[(o << 2) + c] = red[0][c] + red[1][c] + red[2][c] + red[3][c];
}

__global__ __launch_bounds__(256) void prep_xT2(
    const float* __restrict__ X, short* __restrict__ XT2)
{
    __shared__ short T[4][64][72];
    const int tid = threadIdx.x, w = tid >> 6, lane = tid & 63;
    const int l15 = lane & 15, g = lane >> 4;
    const int P0 = blockIdx.x << 8;
    const int n  = P0 >> 12;
    const int qb = (P0 & 4095) + (w << 6);
    const float* xq = X + ((size_t)n << 20) + (size_t)(qb + lane);
    const size_t Gw = (size_t)((P0 + (w << 6)) >> 4);

    for (int co = 0; co < 4; ++co) {
        #pragma unroll
        for (int cq = 0; cq < 4; ++cq) {
            const int c0 = (co << 6) + (cq << 4);
            float v[16];
            #pragma unroll
            for (int j = 0; j < 16; ++j)
                v[j] = xq[(size_t)(c0 + j) << 12];
            short8 s0, s1;
            #pragma unroll
            for (int j = 0; j < 8; ++j) { s0[j] = f2bf(v[j]); s1[j] = f2bf(v[8 + j]); }
            *(short8*)&T[w][lane][cq << 4] = s0;
            *(short8*)&T[w][lane][(cq << 4) + 8] = s1;
        }
        __syncthreads();
        #pragma unroll
        for (int t = 0; t < 4; ++t) {
            #pragma unroll
            for (int kl2 = 0; kl2 < 2; ++kl2) {
                short8 d = *(const short8*)&T[w][(t << 4) + l15][(kl2 << 5) + (g << 3)];
                const int K = (co << 1) + kl2;
                *(short8*)(XT2 + (((Gw + t) << 3 | K) << 9) + (lane << 3)) = d;
            }
        }
        __syncthreads();
    }
}

// Fast GEMM (round-8 body) + contiguous-store epilogue: each global store
// is 64 lanes x 16 B = 1 KB fully contiguous, covering one (o, h,h+1) row pair.
__global__ __launch_bounds__(256, 3) void deconv_gemm_f3(
    const short* __restrict__ XT2, const short* __restrict__ Bg2,
    const float* __restrict__ Bsum, float* __restrict__ Y)
{
    __shared__ float E[4][8][132];   // per-wave reshuffle buffer, 16.9 KB

    const int tid = threadIdx.x;
    int bid = blockIdx.x;
    const int L  = ((bid & 7) << 10) | (bid >> 3);  // XCD-chunked, bijective (8192 = 8*1024)
    const int cb = L & 7;
    const int rb = L >> 3;
    const int p0 = rb << 7;
    const int n  = p0 >> 12;
    const int q0 = p0 & 4095;

    const int wave = tid >> 6, lane = tid & 63;
    const int wm = wave >> 1, wn = wave & 1;
    const int l15 = lane & 15, g = lane >> 4;

    const short* ab = XT2 + (((size_t)((p0 >> 4) + (wm << 2))) << 12) + (lane << 3);
    const short* bb = Bg2 + (((size_t)((cb << 3) + (wn << 2))) << 12) + (lane << 3);

    f32x4 acc[4][4] = {};
    #pragma unroll
    for (int ks = 0; ks < 8; ++ks) {
        const int ko = ks << 9;
        short8 afr[4], bfr[4];
        #pragma unroll
        for (int fm = 0; fm < 4; ++fm) afr[fm] = *(const short8*)(ab + (fm << 12) + ko);
        #pragma unroll
        for (int fn = 0; fn < 4; ++fn) bfr[fn] = *(const short8*)(bb + (fn << 12) + ko);
        #pragma unroll
        for (int fm = 0; fm < 4; ++fm)
            #pragma unroll
            for (int fn = 0; fn < 4; ++fn)
                acc[fm][fn] = __builtin_amdgcn_mfma_f32_16x16x32_bf16(afr[fm], bfr[fn], acc[fm][fn], 0, 0, 0);
    }

    // Epilogue: wave owns one full ih row (iw = fm*16 + g*4 + r) x 64 cols
    // (o' = l15>>2 within fn chunk, kh = (l15>>1)&1, kw = l15&1).
    // Per fn chunk: scatter into E rows (2*o' + kh), w = fm*32+g*8+2r+kw, then
    // store 4x contiguous 1 KB: rows (2s, 2s+1) = (o0f+s, h=2ih+{0,1}).
    const int ih = (q0 >> 6) + wm;
    const int erow = ((l15 >> 1) & 6) + ((l15 >> 1) & 1);   // 2*(l15>>2) + ((l15>>1)&1)
    const int kw = l15 & 1;
    #pragma unroll
    for (int fn = 0; fn < 4; ++fn) {
        const int col = (cb << 7) + (wn << 6) + (fn << 4) + l15;
        const float bv = Bsum[col];
        #pragma unroll
        for (int fm = 0; fm < 4; ++fm) {
            const int wb = (fm << 5) + (g << 3) + kw;
            E[wave][erow][wb]     = acc[fm][fn][0] + bv;
            E[wave][erow][wb + 2] = acc[fm][fn][1] + bv;
            E[wave][erow][wb + 4] = acc[fm][fn][2] + bv;
            E[wave][erow][wb + 6] = acc[fm][fn][3] + bv;
        }
        const int o0f = (cb << 5) + (wn << 4) + (fn << 2);
        #pragma unroll
        for (int s = 0; s < 4; ++s) {
            f32x4 v = *(const f32x4*)&E[wave][(s << 1) + (lane >> 5)][(lane & 31) << 2];
            float* dst = Y + ((((size_t)n << 8) + (o0f + s)) << 14)
                           + ((size_t)((ih << 1) + (lane >> 5)) << 7) + ((lane & 31) << 2);
            *(f32x4*)dst = v;
        }
    }
}

// ---------------- Fallback path (round-4 verified 282 us) ----------------
__global__ __launch_bounds__(256) void prep_wb(
    const float* __restrict__ W, const float* __restrict__ B,
    short* __restrict__ Bg, float* __restrict__ bsum)
{
    const int o = blockIdx.x, c = threadIdx.x;
    const int wave = c >> 6, lane = c & 63;
    f32x4 w = *(const f32x4*)(W + ((size_t)o << 10) + (c << 2));
    #pragma unroll
    for (int kl = 0; kl < 4; ++kl)
        Bg[(size_t)(((o << 2) + kl) << 8) + c] = f2bf(w[kl]);

    f32x4 b = *(const f32x4*)(B + ((size_t)o << 10) + (c << 2));
    #pragma unroll
    for (int off = 32; off >= 1; off >>= 1) {
        b[0] += __shfl_down(b[0], off, 64);
        b[1] += __shfl_down(b[1], off, 64);
        b[2] += __shfl_down(b[2], off, 64);
        b[3] += __shfl_down(b[3], off, 64);
    }
    __shared__ float red[4][4];
    if (lane == 0) { red[wave][0] = b[0]; red[wave][1] = b[1]; red[wave][2] = b[2]; red[wave][3] = b[3]; }
    __syncthreads();
    if (c < 4)
        bsum[(o << 2) + c] = red[0][c] + red[1][c] + red[2][c] + red[3][c];
}

__global__ __launch_bounds__(512, 4) void deconv_gemm_v4(
    const float* __restrict__ X, const short* __restrict__ Bg,
    const float* __restrict__ Bsum, float* __restrict__ Y)
{
    __shared__ short As[2][128 * 32];
    __shared__ short Bs[2][128 * 32];

    const int tid = threadIdx.x;
    int bid = blockIdx.x;
    const int L  = ((bid & 7) << 10) | (bid >> 3);
    const int cb = L & 7;
    const int rb = L >> 3;
    const int p0 = rb << 7;
    const int n  = p0 >> 12;
    const int q0 = p0 & 4095;

    const int wave = tid >> 6, lane = tid & 63;
    const int wm = wave >> 1, wn = wave & 1;
    const int l15 = lane & 15, g = lane >> 4;

    f32x4 acc[2][4] = {};

    const int am  = tid & 127;
    const int akq = tid >> 7;
    const float* xp = X + ((size_t)n << 20) + (size_t)(q0 + am);
    const int aw_idx = am * 32 + (((akq << 3)) ^ ((((am >> 1) & 3)) << 3));
    const int bcol = tid >> 2;
    const int bks  = tid & 3;
    const short* bgp = Bg + ((size_t)((cb << 7) + bcol) << 8) + (bks << 3);
    const int bw_idx = bcol * 32 + (((bks << 3)) ^ ((((bcol >> 1) & 3)) << 3));

    const int mloc = (wm << 5) + l15;
    const int cloc = (wn << 6) + l15;

    float aL[8]; short8 bL;
    #pragma unroll
    for (int j = 0; j < 8; ++j)
        aL[j] = xp[(size_t)((akq << 3) + j) << 12];
    bL = *(const short8*)bgp;
    {
        short8 av;
        #pragma unroll
        for (int j = 0; j < 8; ++j) av[j] = f2bf(aL[j]);
        *(short8*)&As[0][aw_idx] = av;
        *(short8*)&Bs[0][bw_idx] = bL;
    }
    __syncthreads();

    for (int t = 0; t < 8; ++t) {
        const int cur = t & 1;
        if (t < 7) {
            const int c0 = (t + 1) << 5;
            #pragma unroll
            for (int j = 0; j < 8; ++j)
                aL[j] = xp[(size_t)(c0 + (akq << 3) + j) << 12];
            bL = *(const short8*)(bgp + c0);
        }

        short8 afr[2], bfr[4];
        #pragma unroll
        for (int fm = 0; fm < 2; ++fm) {
            const int m = mloc + (fm << 4);
            afr[fm] = *(const short8*)&As[cur][m * 32 + ((g << 3) ^ (((m >> 1) & 3) << 3))];
        }
        #pragma unroll
        for (int fn = 0; fn < 4; ++fn) {
            const int c = cloc + (fn << 4);
            bfr[fn] = *(const short8*)&Bs[cur][c * 32 + ((g << 3) ^ (((c >> 1) & 3) << 3))];
        }
        #pragma unroll
        for (int fm = 0; fm < 2; ++fm)
            #pragma unroll
            for (int fn = 0; fn < 4; ++fn)
                acc[fm][fn] = __builtin_amdgcn_mfma_f32_16x16x32_bf16(afr[fm], bfr[fn], acc[fm][fn], 0, 0, 0);

        if (t < 7) {
            short8 av;
            #pragma unroll
            for (int j = 0; j < 8; ++j) av[j] = f2bf(aL[j]);
            *(short8*)&As[cur ^ 1][aw_idx] = av;
            *(short8*)&Bs[cur ^ 1][bw_idx] = bL;
            __syncthreads();
        }
    }

    const int ihbase = q0 >> 6;
    float bvv[4]; int colv[4];
    #pragma unroll
    for (int fn = 0; fn < 4; ++fn) {
        colv[fn] = (cb << 7) + (wn << 6) + (fn << 4) + l15;
        bvv[fn] = Bsum[colv[fn]];
    }
    #pragma unroll
    for (int fm = 0; fm < 2; ++fm) {
        const int ph = (wm << 5) + (fm << 4);
        const int ih = ihbase + (ph >> 6);
        const int iwb = (((ph & 63) + (g << 2)) << 1);
        #pragma unroll
        for (int fn = 0; fn < 4; ++fn) {
            const int col = colv[fn];
            const int o = col >> 2;
            const int h = (ih << 1) + ((col >> 1) & 1);
            float* yrow = Y + ((((size_t)n << 8) + (size_t)o) << 14) + ((size_t)h << 7);
            const float v0 = acc[fm][fn][0] + bvv[fn];
            const float v1 = acc[fm][fn][1] + bvv[fn];
            const float v2 = acc[fm][fn][2] + bvv[fn];
            const float v3 = acc[fm][fn][3] + bvv[fn];
            const float p0v = __shfl_xor(v0, 1, 64);
            const float p1v = __shfl_xor(v1, 1, 64);
            const float p2v = __shfl_xor(v2, 1, 64);
            const float p3v = __shfl_xor(v3, 1, 64);
            f32x4 st; int w;
            if (!(lane & 1)) { st = (f32x4){v0, p0v, v1, p1v}; w = iwb; }
            else             { st = (f32x4){p2v, v2, p3v, v3}; w = iwb + 4; }
            *(f32x4*)(yrow + w) = st;
        }
    }
}

extern "C" void kernel_launch(void* const* d_in, const int* in_sizes, int n_in,
                              void* d_out, int out_size, void* d_ws, size_t ws_size,
                              hipStream_t stream) {
    const float* X = (const float*)d_in[0];   // batches (32,256,64,64)
    const float* W = (const float*)d_in[1];   // weights (256,256,2,2)
    const float* B = (const float*)d_in[2];   // biases  (256,256,2,2)

    const size_t XT_BYTES = (size_t)131072 * 256 * sizeof(short);   // 64 MiB
    const size_t BG_BYTES = (size_t)1024 * 256 * sizeof(short);     // 512 KiB
    const size_t BS_BYTES = (size_t)1024 * sizeof(float);           // 4 KiB
    const size_t NEED = XT_BYTES + BG_BYTES + BS_BYTES;

    if (ws_size >= NEED) {
        short* XT2  = (short*)d_ws;
        short* Bg2  = (short*)((char*)d_ws + XT_BYTES);
        float* bsum = (float*)((char*)d_ws + XT_BYTES + BG_BYTES);
        prep_wb2<<<256, 256, 0, stream>>>(W, B, Bg2, bsum);
        prep_xT2<<<512, 256, 0, stream>>>(X, XT2);
        deconv_gemm_f3<<<8192, 256, 0, stream>>>(XT2, Bg2, bsum, (float*)d_out);
    } else {
        short* Bg   = (short*)d_ws;
        float* bsum = (float*)((char*)d_ws + BG_BYTES);
        prep_wb<<<256, 256, 0, stream>>>(W, B, Bg, bsum);
        deconv_gemm_v4<<<8192, 512, 0, stream>>>(X, Bg, bsum, (float*)d_out);
    }
}

// Round 12
// 166.835 us; speedup vs baseline: 1.6739x; 1.6739x over previous
//
#include <hip/hip_runtime.h>
#include <hip/hip_bf16.h>

typedef __attribute__((ext_vector_type(8))) short short8;
typedef __attribute__((ext_vector_type(4))) float f32x4;

// X: (32, 256, 64, 64) f32 ; W,B: (256, 256, 2, 2) f32 ; out: (32, 256, 128, 128) f32
// GEMM view: M = 131072 pixels (m = n*4096 + ih*64 + iw), N = 1024 (col = o*4 + kh*2 + kw), K = 256.
//
// Round-12 structure: ONE block owns a 128-pixel tile and computes ALL 1024
// columns for it -> each A-panel is read from HBM exactly once (previous
// rounds re-read A 8x through L3, ~1 GB of hidden traffic). A is staged once
// into LDS in MFMA-fragment order; B (512 KB bf16, fragment-tiled) stays
// L2-resident and is streamed per 128-col chunk. One barrier per block total.

__device__ __forceinline__ short f2bf(float f) {
    union { __hip_bfloat16 h; short s; } u; u.h = __float2bfloat16(f); return u.s;
}

// One-shot prep (verified r8): W -> Bg2 fragment-tiled bf16 [C][K][g,l15][j],
// element (col,k) at ((C*8+K)*64 + g*16 + l15)*8 + j, C=col>>4, l15=col&15,
// K=k>>5, g=(k>>3)&3, j=k&7.  Plus bsum[col] = sum_c biases.
__global__ __launch_bounds__(256) void prep_wb2(
    const float* __restrict__ W, const float* __restrict__ B,
    short* __restrict__ Bg2, float* __restrict__ bsum)
{
    const int o = blockIdx.x, c = threadIdx.x;
    const int wave = c >> 6, lane = c & 63;
    f32x4 w = *(const f32x4*)(W + ((size_t)o << 10) + (c << 2));
    const int C = o >> 2;
    const int K = c >> 5, g = (c >> 3) & 3, j = c & 7;
    #pragma unroll
    for (int kl = 0; kl < 4; ++kl) {
        const int l15 = ((o & 3) << 2) + kl;
        Bg2[(size_t)((((C << 3) | K) << 9) + (((g << 4) | l15) << 3) + j)] = f2bf(w[kl]);
    }

    f32x4 b = *(const f32x4*)(B + ((size_t)o << 10) + (c << 2));
    #pragma unroll
    for (int off = 32; off >= 1; off >>= 1) {
        b[0] += __shfl_down(b[0], off, 64);
        b[1] += __shfl_down(b[1], off, 64);
        b[2] += __shfl_down(b[2], off, 64);
        b[3] += __shfl_down(b[3], off, 64);
    }
    __shared__ float red[4][4];
    if (lane == 0) { red[wave][0] = b[0]; red[wave][1] = b[1]; red[wave][2] = b[2]; red[wave][3] = b[3]; }
    __syncthreads();
    if (c < 4)
        bsum[(o << 2) + c] = red[0][c] + red[1][c] + red[2][c] + red[3][c];
}

// Fused kernel: 1024 blocks x 512 thr (8 waves = 2m x 4n).
// LDS A: fragment-tiled [(G*8+K)*512 + g*128 + l15*8 + e] shorts = 64 KB.
// Per chunk cc (0..7): wave computes 64 pixels x 32 cols, acc[4][2].
__global__ __launch_bounds__(512, 4) void deconv_fused(
    const float* __restrict__ X, const short* __restrict__ Bg2,
    const float* __restrict__ Bsum, float* __restrict__ Y)
{
    __shared__ short A[8 * 8 * 512];   // 64 KB

    const int tid = threadIdx.x;
    const int bid = blockIdx.x;        // 1024 blocks; no swizzle (no inter-block A sharing)
    const int p0 = bid << 7;           // pixel base
    const int n  = p0 >> 12;
    const int q0 = p0 & 4095;

    const int wave = tid >> 6, lane = tid & 63;
    const int wm = wave >> 2, wn = wave & 3;   // 2 x 4 wave grid
    const int l15 = lane & 15, g = lane >> 4;

    // ---- stage A once: thread owns pixel am, k-quarter kq (64 k's) ----
    const int am = tid & 127, kq = tid >> 7;
    const float* xp = X + ((size_t)n << 20) + (size_t)(q0 + am);
    const int Gs = am >> 4, a15 = am & 15;
    #pragma unroll
    for (int jj = 0; jj < 8; ++jj) {           // k-octet within quarter
        float v[8];
        #pragma unroll
        for (int e = 0; e < 8; ++e)
            v[e] = xp[(size_t)((kq << 6) + (jj << 3) + e) << 12];   // 256B/wave coalesced
        short8 s;
        #pragma unroll
        for (int e = 0; e < 8; ++e) s[e] = f2bf(v[e]);
        const int K = (kq << 1) + (jj >> 2), gg = jj & 3;
        *(short8*)&A[(((Gs << 3) + K) << 9) + (gg << 7) + (a15 << 3)] = s;
    }
    __syncthreads();   // the only barrier

    // ---- main loop over 8 col-chunks of 128 ----
    // B frag addr (shorts): (cc<<15) + (wn<<13) + (fn<<12) + (K<<9) + lane*8
    const short* bb = Bg2 + (wn << 13) + (lane << 3);
    // A frag addr (shorts): (wm<<14) + (fm<<12) + (K<<9) + lane*8  (conflict-free b128)
    const int abase = (wm << 14) + (lane << 3);
    const int ih = (q0 >> 6) + wm;

    for (int cc = 0; cc < 8; ++cc) {
        f32x4 acc[4][2] = {};
        #pragma unroll
        for (int K = 0; K < 8; ++K) {
            const short8 b0 = *(const short8*)(bb + (cc << 15) + (K << 9));
            const short8 b1 = *(const short8*)(bb + (cc << 15) + (1 << 12) + (K << 9));
            const short8 a0 = *(const short8*)&A[abase + (0 << 12) + (K << 9)];
            const short8 a1 = *(const short8*)&A[abase + (1 << 12) + (K << 9)];
            const short8 a2 = *(const short8*)&A[abase + (2 << 12) + (K << 9)];
            const short8 a3 = *(const short8*)&A[abase + (3 << 12) + (K << 9)];
            acc[0][0] = __builtin_amdgcn_mfma_f32_16x16x32_bf16(a0, b0, acc[0][0], 0, 0, 0);
            acc[0][1] = __builtin_amdgcn_mfma_f32_16x16x32_bf16(a0, b1, acc[0][1], 0, 0, 0);
            acc[1][0] = __builtin_amdgcn_mfma_f32_16x16x32_bf16(a1, b0, acc[1][0], 0, 0, 0);
            acc[1][1] = __builtin_amdgcn_mfma_f32_16x16x32_bf16(a1, b1, acc[1][1], 0, 0, 0);
            acc[2][0] = __builtin_amdgcn_mfma_f32_16x16x32_bf16(a2, b0, acc[2][0], 0, 0, 0);
            acc[2][1] = __builtin_amdgcn_mfma_f32_16x16x32_bf16(a2, b1, acc[2][1], 0, 0, 0);
            acc[3][0] = __builtin_amdgcn_mfma_f32_16x16x32_bf16(a3, b0, acc[3][0], 0, 0, 0);
            acc[3][1] = __builtin_amdgcn_mfma_f32_16x16x32_bf16(a3, b1, acc[3][1], 0, 0, 0);
        }

        // Epilogue for this chunk (mapping verified rounds 1-11):
        // pixel = p0 + wm*64 + fm*16 + 4g + r; col = cc*128 + wn*32 + fn*16 + l15.
        // lane^1 pair-swap merges kw=0/1 so each lane stores one contiguous float4.
        #pragma unroll
        for (int fn = 0; fn < 2; ++fn) {
            const int col = (cc << 7) + (wn << 5) + (fn << 4) + l15;
            const float bv = Bsum[col];
            const int o = col >> 2;
            const int h = (ih << 1) + ((col >> 1) & 1);
            float* yrow = Y + ((((size_t)n << 8) + (size_t)o) << 14) + ((size_t)h << 7);
            #pragma unroll
            for (int fm = 0; fm < 4; ++fm) {
                const float v0 = acc[fm][fn][0] + bv;
                const float v1 = acc[fm][fn][1] + bv;
                const float v2 = acc[fm][fn][2] + bv;
                const float v3 = acc[fm][fn][3] + bv;
                const float p0v = __shfl_xor(v0, 1, 64);
                const float p1v = __shfl_xor(v1, 1, 64);
                const float p2v = __shfl_xor(v2, 1, 64);
                const float p3v = __shfl_xor(v3, 1, 64);
                const int iw0 = (fm << 4) + (g << 2);
                f32x4 st; int w;
                if (!(lane & 1)) { st = (f32x4){v0, p0v, v1, p1v}; w = (iw0 << 1); }
                else             { st = (f32x4){p2v, v2, p3v, v3}; w = (iw0 << 1) + 4; }
                *(f32x4*)(yrow + w) = st;
            }
        }
    }
}

extern "C" void kernel_launch(void* const* d_in, const int* in_sizes, int n_in,
                              void* d_out, int out_size, void* d_ws, size_t ws_size,
                              hipStream_t stream) {
    const float* X = (const float*)d_in[0];   // batches (32,256,64,64)
    const float* W = (const float*)d_in[1];   // weights (256,256,2,2)
    const float* B = (const float*)d_in[2];   // biases  (256,256,2,2)

    short* Bg2  = (short*)d_ws;                                   // 512 KiB
    float* bsum = (float*)((char*)d_ws + (size_t)1024 * 256 * sizeof(short));  // 4 KiB

    prep_wb2<<<256, 256, 0, stream>>>(W, B, Bg2, bsum);
    deconv_fused<<<1024, 512, 0, stream>>>(X, Bg2, bsum, (float*)d_out);
}

// Round 13
// 164.179 us; speedup vs baseline: 1.7010x; 1.0162x over previous
//
#include <hip/hip_runtime.h>
#include <hip/hip_bf16.h>

typedef __attribute__((ext_vector_type(8))) short short8;
typedef __attribute__((ext_vector_type(4))) float f32x4;

// X: (32, 256, 64, 64) f32 ; W,B: (256, 256, 2, 2) f32 ; out: (32, 256, 128, 128) f32
// GEMM view: M = 131072 pixels, N = 1024 (col = o*4 + kh*2 + kw), K = 256.
//
// Round-13: r12 structure (one block computes ALL 1024 cols for its pixel
// tile -> A read from HBM exactly once) with BM 128->64: 32 KB LDS ->
// 4 blocks/CU (was 2) for better stage/compute/drain overlap.

__device__ __forceinline__ short f2bf(float f) {
    union { __hip_bfloat16 h; short s; } u; u.h = __float2bfloat16(f); return u.s;
}

// One-shot prep (verified r8/r12): W -> Bg2 fragment-tiled bf16, element
// (col,k) at ((C*8+K)*64 + g*16 + l15)*8 + j; C=col>>4, l15=col&15, K=k>>5,
// g=(k>>3)&3, j=k&7.  Plus bsum[col] = sum_c biases.
__global__ __launch_bounds__(256) void prep_wb2(
    const float* __restrict__ W, const float* __restrict__ B,
    short* __restrict__ Bg2, float* __restrict__ bsum)
{
    const int o = blockIdx.x, c = threadIdx.x;
    const int wave = c >> 6, lane = c & 63;
    f32x4 w = *(const f32x4*)(W + ((size_t)o << 10) + (c << 2));
    const int C = o >> 2;
    const int K = c >> 5, g = (c >> 3) & 3, j = c & 7;
    #pragma unroll
    for (int kl = 0; kl < 4; ++kl) {
        const int l15 = ((o & 3) << 2) + kl;
        Bg2[(size_t)((((C << 3) | K) << 9) + (((g << 4) | l15) << 3) + j)] = f2bf(w[kl]);
    }

    f32x4 b = *(const f32x4*)(B + ((size_t)o << 10) + (c << 2));
    #pragma unroll
    for (int off = 32; off >= 1; off >>= 1) {
        b[0] += __shfl_down(b[0], off, 64);
        b[1] += __shfl_down(b[1], off, 64);
        b[2] += __shfl_down(b[2], off, 64);
        b[3] += __shfl_down(b[3], off, 64);
    }
    __shared__ float red[4][4];
    if (lane == 0) { red[wave][0] = b[0]; red[wave][1] = b[1]; red[wave][2] = b[2]; red[wave][3] = b[3]; }
    __syncthreads();
    if (c < 4)
        bsum[(o << 2) + c] = red[0][c] + red[1][c] + red[2][c] + red[3][c];
}

// Fused kernel: 2048 blocks x 256 thr (4 waves). Block owns 64 pixels (one
// ih row), computes all 1024 cols in 8 chunks of 128 (32 cols/wave/chunk).
// LDS A fragment-tiled: [(G*8+K)*512 + g*128 + l15*8 + e] shorts = 32 KB.
__global__ __launch_bounds__(256, 4) void deconv_fused64(
    const float* __restrict__ X, const short* __restrict__ Bg2,
    const float* __restrict__ Bsum, float* __restrict__ Y)
{
    __shared__ short A[4 * 8 * 512];   // 32 KB

    const int tid = threadIdx.x;
    const int bid = blockIdx.x;        // 2048 blocks
    const int p0 = bid << 6;           // pixel base (64 per block)
    const int n  = p0 >> 12;
    const int q0 = p0 & 4095;

    const int wave = tid >> 6, lane = tid & 63;   // wave == wn (0..3)
    const int l15 = lane & 15, g = lane >> 4;

    // ---- stage A once: thread owns pixel am (0..63), k-quarter kq ----
    const int am = tid & 63, kq = tid >> 6;
    const float* xp = X + ((size_t)n << 20) + (size_t)(q0 + am);
    const int Gs = am >> 4, a15 = am & 15;
    #pragma unroll
    for (int jj = 0; jj < 8; ++jj) {           // k-octet within quarter
        float v[8];
        #pragma unroll
        for (int e = 0; e < 8; ++e)
            v[e] = xp[(size_t)((kq << 6) + (jj << 3) + e) << 12];   // 256B/wave coalesced
        short8 s;
        #pragma unroll
        for (int e = 0; e < 8; ++e) s[e] = f2bf(v[e]);
        const int K = (kq << 1) + (jj >> 2), gg = jj & 3;
        *(short8*)&A[(((Gs << 3) + K) << 9) + (gg << 7) + (a15 << 3)] = s;
    }
    __syncthreads();   // the only barrier

    // ---- main loop over 8 col-chunks of 128 ----
    // B frag (shorts): (cc<<15) + (wave<<13) + (fn<<12) + (K<<9) + lane*8
    const short* bb = Bg2 + (wave << 13) + (lane << 3);
    // A frag (shorts): (fm<<12) + (K<<9) + lane*8   (conflict-free b128)
    const int abase = lane << 3;
    const int ih = q0 >> 6;

    for (int cc = 0; cc < 8; ++cc) {
        f32x4 acc[4][2] = {};
        #pragma unroll
        for (int K = 0; K < 8; ++K) {
            const short8 b0 = *(const short8*)(bb + (cc << 15) + (K << 9));
            const short8 b1 = *(const short8*)(bb + (cc << 15) + (1 << 12) + (K << 9));
            const short8 a0 = *(const short8*)&A[abase + (0 << 12) + (K << 9)];
            const short8 a1 = *(const short8*)&A[abase + (1 << 12) + (K << 9)];
            const short8 a2 = *(const short8*)&A[abase + (2 << 12) + (K << 9)];
            const short8 a3 = *(const short8*)&A[abase + (3 << 12) + (K << 9)];
            acc[0][0] = __builtin_amdgcn_mfma_f32_16x16x32_bf16(a0, b0, acc[0][0], 0, 0, 0);
            acc[0][1] = __builtin_amdgcn_mfma_f32_16x16x32_bf16(a0, b1, acc[0][1], 0, 0, 0);
            acc[1][0] = __builtin_amdgcn_mfma_f32_16x16x32_bf16(a1, b0, acc[1][0], 0, 0, 0);
            acc[1][1] = __builtin_amdgcn_mfma_f32_16x16x32_bf16(a1, b1, acc[1][1], 0, 0, 0);
            acc[2][0] = __builtin_amdgcn_mfma_f32_16x16x32_bf16(a2, b0, acc[2][0], 0, 0, 0);
            acc[2][1] = __builtin_amdgcn_mfma_f32_16x16x32_bf16(a2, b1, acc[2][1], 0, 0, 0);
            acc[3][0] = __builtin_amdgcn_mfma_f32_16x16x32_bf16(a3, b0, acc[3][0], 0, 0, 0);
            acc[3][1] = __builtin_amdgcn_mfma_f32_16x16x32_bf16(a3, b1, acc[3][1], 0, 0, 0);
        }

        // Epilogue (mapping verified rounds 1-12): pixel = p0 + fm*16 + 4g + r;
        // col = cc*128 + wave*32 + fn*16 + l15. lane^1 pair-swap merges kw=0/1
        // so each lane stores one contiguous float4.
        #pragma unroll
        for (int fn = 0; fn < 2; ++fn) {
            const int col = (cc << 7) + (wave << 5) + (fn << 4) + l15;
            const float bv = Bsum[col];
            const int o = col >> 2;
            const int h = (ih << 1) + ((col >> 1) & 1);
            float* yrow = Y + ((((size_t)n << 8) + (size_t)o) << 14) + ((size_t)h << 7);
            #pragma unroll
            for (int fm = 0; fm < 4; ++fm) {
                const float v0 = acc[fm][fn][0] + bv;
                const float v1 = acc[fm][fn][1] + bv;
                const float v2 = acc[fm][fn][2] + bv;
                const float v3 = acc[fm][fn][3] + bv;
                const float p0v = __shfl_xor(v0, 1, 64);
                const float p1v = __shfl_xor(v1, 1, 64);
                const float p2v = __shfl_xor(v2, 1, 64);
                const float p3v = __shfl_xor(v3, 1, 64);
                const int iw0 = (fm << 4) + (g << 2);
                f32x4 st; int w;
                if (!(lane & 1)) { st = (f32x4){v0, p0v, v1, p1v}; w = (iw0 << 1); }
                else             { st = (f32x4){p2v, v2, p3v, v3}; w = (iw0 << 1) + 4; }
                *(f32x4*)(yrow + w) = st;
            }
        }
    }
}

extern "C" void kernel_launch(void* const* d_in, const int* in_sizes, int n_in,
                              void* d_out, int out_size, void* d_ws, size_t ws_size,
                              hipStream_t stream) {
    const float* X = (const float*)d_in[0];   // batches (32,256,64,64)
    const float* W = (const float*)d_in[1];   // weights (256,256,2,2)
    const float* B = (const float*)d_in[2];   // biases  (256,256,2,2)

    short* Bg2  = (short*)d_ws;                                   // 512 KiB
    float* bsum = (float*)((char*)d_ws + (size_t)1024 * 256 * sizeof(short));  // 4 KiB

    prep_wb2<<<256, 256, 0, stream>>>(W, B, Bg2, bsum);
    deconv_fused64<<<2048, 256, 0, stream>>>(X, Bg2, bsum, (float*)d_out);
}

// Round 14
// 130.247 us; speedup vs baseline: 2.1442x; 1.2605x over previous
//
#include <hip/hip_runtime.h>
#include <hip/hip_bf16.h>

typedef __attribute__((ext_vector_type(8))) short short8;
typedef __attribute__((ext_vector_type(4))) float f32x4;

// X: (32, 256, 64, 64) f32 ; W,B: (256, 256, 2, 2) f32 ; out: (32, 256, 128, 128) f32
// GEMM view: M = 131072 pixels, N = 1024 (col = o*4 + kh*2 + kw), K = 256.
//
// Round-14: r13 structure (one block = 64 pixels, ALL 1024 cols, A read from
// HBM exactly once, 4 blocks/CU) + ONE change: Y stores are nontemporal
// (Y is never re-read; keep the 537 MB write stream from evicting the
// L2-resident Bg2 weight tile).

__device__ __forceinline__ short f2bf(float f) {
    union { __hip_bfloat16 h; short s; } u; u.h = __float2bfloat16(f); return u.s;
}

// One-shot prep (verified r8/r12): W -> Bg2 fragment-tiled bf16, element
// (col,k) at ((C*8+K)*64 + g*16 + l15)*8 + j; C=col>>4, l15=col&15, K=k>>5,
// g=(k>>3)&3, j=k&7.  Plus bsum[col] = sum_c biases.
__global__ __launch_bounds__(256) void prep_wb2(
    const float* __restrict__ W, const float* __restrict__ B,
    short* __restrict__ Bg2, float* __restrict__ bsum)
{
    const int o = blockIdx.x, c = threadIdx.x;
    const int wave = c >> 6, lane = c & 63;
    f32x4 w = *(const f32x4*)(W + ((size_t)o << 10) + (c << 2));
    const int C = o >> 2;
    const int K = c >> 5, g = (c >> 3) & 3, j = c & 7;
    #pragma unroll
    for (int kl = 0; kl < 4; ++kl) {
        const int l15 = ((o & 3) << 2) + kl;
        Bg2[(size_t)((((C << 3) | K) << 9) + (((g << 4) | l15) << 3) + j)] = f2bf(w[kl]);
    }

    f32x4 b = *(const f32x4*)(B + ((size_t)o << 10) + (c << 2));
    #pragma unroll
    for (int off = 32; off >= 1; off >>= 1) {
        b[0] += __shfl_down(b[0], off, 64);
        b[1] += __shfl_down(b[1], off, 64);
        b[2] += __shfl_down(b[2], off, 64);
        b[3] += __shfl_down(b[3], off, 64);
    }
    __shared__ float red[4][4];
    if (lane == 0) { red[wave][0] = b[0]; red[wave][1] = b[1]; red[wave][2] = b[2]; red[wave][3] = b[3]; }
    __syncthreads();
    if (c < 4)
        bsum[(o << 2) + c] = red[0][c] + red[1][c] + red[2][c] + red[3][c];
}

// Fused kernel: 2048 blocks x 256 thr (4 waves). Block owns 64 pixels (one
// ih row), computes all 1024 cols in 8 chunks of 128 (32 cols/wave/chunk).
// LDS A fragment-tiled: [(G*8+K)*512 + g*128 + l15*8 + e] shorts = 32 KB.
__global__ __launch_bounds__(256, 4) void deconv_fused64(
    const float* __restrict__ X, const short* __restrict__ Bg2,
    const float* __restrict__ Bsum, float* __restrict__ Y)
{
    __shared__ short A[4 * 8 * 512];   // 32 KB

    const int tid = threadIdx.x;
    const int bid = blockIdx.x;        // 2048 blocks
    const int p0 = bid << 6;           // pixel base (64 per block)
    const int n  = p0 >> 12;
    const int q0 = p0 & 4095;

    const int wave = tid >> 6, lane = tid & 63;   // wave == wn (0..3)
    const int l15 = lane & 15, g = lane >> 4;

    // ---- stage A once: thread owns pixel am (0..63), k-quarter kq ----
    const int am = tid & 63, kq = tid >> 6;
    const float* xp = X + ((size_t)n << 20) + (size_t)(q0 + am);
    const int Gs = am >> 4, a15 = am & 15;
    #pragma unroll
    for (int jj = 0; jj < 8; ++jj) {           // k-octet within quarter
        float v[8];
        #pragma unroll
        for (int e = 0; e < 8; ++e)
            v[e] = xp[(size_t)((kq << 6) + (jj << 3) + e) << 12];   // 256B/wave coalesced
        short8 s;
        #pragma unroll
        for (int e = 0; e < 8; ++e) s[e] = f2bf(v[e]);
        const int K = (kq << 1) + (jj >> 2), gg = jj & 3;
        *(short8*)&A[(((Gs << 3) + K) << 9) + (gg << 7) + (a15 << 3)] = s;
    }
    __syncthreads();   // the only barrier

    // ---- main loop over 8 col-chunks of 128 ----
    // B frag (shorts): (cc<<15) + (wave<<13) + (fn<<12) + (K<<9) + lane*8
    const short* bb = Bg2 + (wave << 13) + (lane << 3);
    // A frag (shorts): (fm<<12) + (K<<9) + lane*8   (conflict-free b128)
    const int abase = lane << 3;
    const int ih = q0 >> 6;

    for (int cc = 0; cc < 8; ++cc) {
        f32x4 acc[4][2] = {};
        #pragma unroll
        for (int K = 0; K < 8; ++K) {
            const short8 b0 = *(const short8*)(bb + (cc << 15) + (K << 9));
            const short8 b1 = *(const short8*)(bb + (cc << 15) + (1 << 12) + (K << 9));
            const short8 a0 = *(const short8*)&A[abase + (0 << 12) + (K << 9)];
            const short8 a1 = *(const short8*)&A[abase + (1 << 12) + (K << 9)];
            const short8 a2 = *(const short8*)&A[abase + (2 << 12) + (K << 9)];
            const short8 a3 = *(const short8*)&A[abase + (3 << 12) + (K << 9)];
            acc[0][0] = __builtin_amdgcn_mfma_f32_16x16x32_bf16(a0, b0, acc[0][0], 0, 0, 0);
            acc[0][1] = __builtin_amdgcn_mfma_f32_16x16x32_bf16(a0, b1, acc[0][1], 0, 0, 0);
            acc[1][0] = __builtin_amdgcn_mfma_f32_16x16x32_bf16(a1, b0, acc[1][0], 0, 0, 0);
            acc[1][1] = __builtin_amdgcn_mfma_f32_16x16x32_bf16(a1, b1, acc[1][1], 0, 0, 0);
            acc[2][0] = __builtin_amdgcn_mfma_f32_16x16x32_bf16(a2, b0, acc[2][0], 0, 0, 0);
            acc[2][1] = __builtin_amdgcn_mfma_f32_16x16x32_bf16(a2, b1, acc[2][1], 0, 0, 0);
            acc[3][0] = __builtin_amdgcn_mfma_f32_16x16x32_bf16(a3, b0, acc[3][0], 0, 0, 0);
            acc[3][1] = __builtin_amdgcn_mfma_f32_16x16x32_bf16(a3, b1, acc[3][1], 0, 0, 0);
        }

        // Epilogue (mapping verified rounds 1-13): pixel = p0 + fm*16 + 4g + r;
        // col = cc*128 + wave*32 + fn*16 + l15. lane^1 pair-swap merges kw=0/1
        // so each lane stores one contiguous float4 — now NONTEMPORAL.
        #pragma unroll
        for (int fn = 0; fn < 2; ++fn) {
            const int col = (cc << 7) + (wave << 5) + (fn << 4) + l15;
            const float bv = Bsum[col];
            const int o = col >> 2;
            const int h = (ih << 1) + ((col >> 1) & 1);
            float* yrow = Y + ((((size_t)n << 8) + (size_t)o) << 14) + ((size_t)h << 7);
            #pragma unroll
            for (int fm = 0; fm < 4; ++fm) {
                const float v0 = acc[fm][fn][0] + bv;
                const float v1 = acc[fm][fn][1] + bv;
                const float v2 = acc[fm][fn][2] + bv;
                const float v3 = acc[fm][fn][3] + bv;
                const float p0v = __shfl_xor(v0, 1, 64);
                const float p1v = __shfl_xor(v1, 1, 64);
                const float p2v = __shfl_xor(v2, 1, 64);
                const float p3v = __shfl_xor(v3, 1, 64);
                const int iw0 = (fm << 4) + (g << 2);
                f32x4 st; int w;
                if (!(lane & 1)) { st = (f32x4){v0, p0v, v1, p1v}; w = (iw0 << 1); }
                else             { st = (f32x4){p2v, v2, p3v, v3}; w = (iw0 << 1) + 4; }
                __builtin_nontemporal_store(st, (f32x4*)(yrow + w));
            }
        }
    }
}

extern "C" void kernel_launch(void* const* d_in, const int* in_sizes, int n_in,
                              void* d_out, int out_size, void* d_ws, size_t ws_size,
                              hipStream_t stream) {
    const float* X = (const float*)d_in[0];   // batches (32,256,64,64)
    const float* W = (const float*)d_in[1];   // weights (256,256,2,2)
    const float* B = (const float*)d_in[2];   // biases  (256,256,2,2)

    short* Bg2  = (short*)d_ws;                                   // 512 KiB
    float* bsum = (float*)((char*)d_ws + (size_t)1024 * 256 * sizeof(short));  // 4 KiB

    prep_wb2<<<256, 256, 0, stream>>>(W, B, Bg2, bsum);
    deconv_fused64<<<2048, 256, 0, stream>>>(X, Bg2, bsum, (float*)d_out);
}